// Round 4
// baseline (284.693 us; speedup 1.0000x reference)
//
#include <hip/hip_runtime.h>
#include <math.h>

#define B_SIZE 8192
#define NVERT 778
#define NP 135

// ---- workspace layout (floats) ---- total 137536 floats = 550 KB (L2-resident)
#define OFF_JK   0        // 48
#define OFF_REL  48       // 48
#define OFF_C1   96       // 336
#define OFF_C0   448      // 1008 (16B aligned)
#define OFF_P    1456     // 135*1008 = 136080 (16B aligned)
#define WS_END   137536

__device__ inline void quat2mat_dev(float qw, float qx, float qy, float qz, float* R) {
  float n = sqrtf(qw*qw + qx*qx + qy*qy + qz*qz);
  float w = qw/n, x = qx/n, y = qy/n, z = qz/n;
  float w2=w*w, x2=x*x, y2=y*y, z2=z*z;
  float wx=w*x, wy=w*y, wz=w*z, xy=x*y, xz=x*z, yz=y*z;
  R[0]=w2+x2-y2-z2; R[1]=2.f*xy-2.f*wz; R[2]=2.f*wy+2.f*xz;
  R[3]=2.f*wz+2.f*xy; R[4]=w2-x2+y2-z2; R[5]=2.f*yz-2.f*wx;
  R[6]=2.f*xz-2.f*wy; R[7]=2.f*wx+2.f*yz; R[8]=w2-x2-y2+z2;
}

__device__ inline void rodrigues_dev(float tx, float ty, float tz, float* R) {
  float ax = tx + 1e-8f, ay = ty + 1e-8f, az = tz + 1e-8f;
  float angle = sqrtf(ax*ax + ay*ay + az*az);
  float nx = tx/angle, ny = ty/angle, nz = tz/angle;
  float half = 0.5f*angle;
  float cw = cosf(half), sw = sinf(half);
  quat2mat_dev(cw, sw*nx, sw*ny, sw*nz, R);
}

__device__ inline void write_A(float* A, const float* G, const float* jk) {
  #pragma unroll
  for (int c = 0; c < 3; ++c) {
    float g0 = G[c*3+0], g1 = G[c*3+1], g2 = G[c*3+2];
    A[c*4+0] = g0; A[c*4+1] = g1; A[c*4+2] = g2;
    A[c*4+3] = G[9+c] - (g0*jk[0] + g1*jk[1] + g2*jk[2]);
  }
}

// K1: Jk(16x3) + rel only (v_shaped kept in LDS). One block.
__global__ void k1_shape(const float* __restrict__ user_shape,
                         const float* __restrict__ v_template,
                         const float* __restrict__ shapedirs,
                         const float* __restrict__ J_regressor,
                         float* __restrict__ ws) {
  __shared__ float sh[10];
  __shared__ float vs[2334];
  __shared__ float red[256][49];
  __shared__ float jk[48];
  int tid = threadIdx.x;
  if (tid < 10) sh[tid] = user_shape[tid];
  __syncthreads();
  for (int e = tid; e < 2334; e += 256) {
    float acc = v_template[e];
    #pragma unroll
    for (int s = 0; s < 10; ++s) acc += sh[s]*shapedirs[s*2334 + e];
    vs[e] = acc;
  }
  float part[48];
  #pragma unroll
  for (int k = 0; k < 48; ++k) part[k] = 0.f;
  __syncthreads();
  for (int v = tid; v < NVERT; v += 256) {
    float v0 = vs[3*v+0], v1 = vs[3*v+1], v2 = vs[3*v+2];
    #pragma unroll
    for (int j = 0; j < 16; ++j) {
      float r = J_regressor[v*21 + j];
      part[j*3+0] += r*v0; part[j*3+1] += r*v1; part[j*3+2] += r*v2;
    }
  }
  #pragma unroll
  for (int k = 0; k < 48; ++k) red[tid][k] = part[k];
  __syncthreads();
  if (tid < 48) {
    float s = 0.f;
    for (int t = 0; t < 256; ++t) s += red[t][tid];
    jk[tid] = s;
    ws[OFF_JK + tid] = s;
  }
  __syncthreads();
  if (tid < 48) {
    int j = tid/3, c = tid - j*3;
    float r;
    if (j == 0) r = jk[c];
    else {
      int par = (((j-1) % 3) == 0) ? 0 : (j-1);
      r = jk[j*3+c] - jk[par*3+c];
    }
    ws[OFF_REL + tid] = r;
  }
}

// K3: split-K GEMM -> atomicAdd into P/C0/C1 (zeroed by memset). v_shaped computed inline.
// grid = 26 col-groups x 8 ksplit; block 192 (168 MAC-active).
__global__ __launch_bounds__(192) void k3_pgemm(const float* __restrict__ J_regressor,
                                                const float* __restrict__ weights,
                                                const float* __restrict__ posedirs,
                                                const float* __restrict__ user_shape,
                                                const float* __restrict__ v_template,
                                                const float* __restrict__ shapedirs,
                                                float* __restrict__ ws) {
  __shared__ float sJR[64*21];
  __shared__ float sW [64*16];
  __shared__ float sB [64*16];
  __shared__ float ush[10];
  int tid = threadIdx.x;
  if (tid < 10) ush[tid] = user_shape[tid];
  int ng = blockIdx.x % 26;
  int ks = blockIdx.x / 26;
  int vbeg = ks*98;
  int vend = min(NVERT, vbeg + 98);

  int cg = (tid < 84) ? 0 : 1;
  int r4 = (tid < 84) ? tid : tid - 84;
  bool act = (tid < 168);
  int q2 = 4*r4;
  int j2 = q2 >> 4;
  int jb = q2 & 15;

  float acc[4][8];
  #pragma unroll
  for (int r = 0; r < 4; ++r)
    #pragma unroll
    for (int s = 0; s < 8; ++s) acc[r][s] = 0.f;

  for (int v0 = vbeg; v0 < vend; v0 += 64) {
    int kt = min(64, vend - v0);
    __syncthreads();
    for (int idx = tid; idx < kt*21; idx += 192) sJR[idx] = J_regressor[v0*21 + idx];
    for (int idx = tid; idx < kt*16; idx += 192) sW[idx]  = weights[v0*16 + idx];
    for (int idx = tid; idx < 16*64; idx += 192) {
      int s = idx >> 6, iv = idx & 63;
      if (iv < kt) {
        int ec = ng*16 + s;
        float val;
        if (ec > 408) val = 0.f;
        else if (ec == 408) val = 1.f;
        else {
          int c = ec / 136, pp = ec - c*136;
          int e = 3*(v0+iv) + c;
          if (pp == 135) {
            float t = v_template[e];
            #pragma unroll
            for (int s0 = 0; s0 < 10; ++s0) t += ush[s0]*shapedirs[s0*2334 + e];
            val = t;
          } else {
            val = posedirs[pp*2334 + e];
          }
        }
        sB[iv*16 + s] = val;
      }
    }
    __syncthreads();
    if (act) {
      for (int i = 0; i < kt; ++i) {
        float jr = sJR[i*21 + j2];
        float4 w4 = *(const float4*)&sW[i*16 + jb];
        float4 b0 = *(const float4*)&sB[i*16 + cg*8];
        float4 b1 = *(const float4*)&sB[i*16 + cg*8 + 4];
        float wv[4] = {w4.x, w4.y, w4.z, w4.w};
        #pragma unroll
        for (int r = 0; r < 4; ++r) {
          float s2 = jr * wv[r];
          acc[r][0] += s2*b0.x; acc[r][1] += s2*b0.y;
          acc[r][2] += s2*b0.z; acc[r][3] += s2*b0.w;
          acc[r][4] += s2*b1.x; acc[r][5] += s2*b1.y;
          acc[r][6] += s2*b1.z; acc[r][7] += s2*b1.w;
        }
      }
    }
  }
  if (act) {
    #pragma unroll
    for (int s = 0; s < 8; ++s) {
      int ec = ng*16 + cg*8 + s;
      if (ec > 408) continue;
      #pragma unroll
      for (int r = 0; r < 4; ++r) {
        float v = acc[r][s];
        int q2r = q2 + r;
        if (ec == 408) {
          atomicAdd(ws + OFF_C1 + q2r, v);
        } else {
          int c = ec / 136, pp = ec - c*136;
          if (pp == 135) atomicAdd(ws + OFF_C0 + q2r*3 + c, v);
          else           atomicAdd(ws + OFF_P + (size_t)pp*1008 + q2r*3 + c, v);
        }
      }
    }
  }
}

// K5: fused pose (prologue, in-LDS) + register-tiled GEMM over a j2-half + A-contraction.
// grid 1024: (512 b-blocks of 16) x (2 j2-halves: j2 0..9 / 10..20). block 320.
__global__ __launch_bounds__(320) void k5_main(const float* __restrict__ theta,
                                               const float* __restrict__ delta_quat,
                                               const float* __restrict__ init_quat,
                                               const float* __restrict__ init_trans,
                                               const float* __restrict__ ws,
                                               float* __restrict__ out) {
  __shared__ __align__(16) float s_pf[16*136];   // 8704 B
  __shared__ __align__(16) float s_A [16*192];   // 12288 B
  __shared__ float s_C1[336];                    // 1344 B
  __shared__ __align__(16) float s_PM[4256];     // 17024 B: P chunk / M spill union
  int tid = threadIdx.x;
  int bh = blockIdx.x & 1;
  int b0 = (blockIdx.x >> 1) * 16;
  int j2base = bh ? 10 : 0;
  int NJ2H  = bh ? 11 : 10;
  int QF4   = NJ2H * 12;     // 120 / 132 float4 columns in this half
  int HQ    = QF4 >> 1;      // 60 / 66
  int RS4   = QF4 + 1;       // odd f4 row stride for M spill
  int RSfl  = RS4 * 4;

  // ---- pose prologue: 96 threads = 16 b x 6 units ----
  if (tid < 96) {
    int bb = tid / 6, u = tid - 6*bb;
    int b = b0 + bb;
    float* pf   = s_pf + bb*136;
    float* Ar   = s_A  + bb*192;
    const float* Jk  = ws + OFF_JK;
    const float* rel = ws + OFF_REL;
    float w1=delta_quat[b*4+0], x1=delta_quat[b*4+1], y1=delta_quat[b*4+2], z1=delta_quat[b*4+3];
    float w2=init_quat[0], x2=init_quat[1], y2=init_quat[2], z2=init_quat[3];
    float qw = w1*w2 - x1*x2 - y1*y2 - z1*z2;
    float qx = w1*x2 + x1*w2 + y1*z2 - z1*y2;
    float qy = w1*y2 - x1*z2 + y1*w2 + z1*x2;
    float qz = w1*z2 + x1*y2 - y1*x2 + z1*w2;
    float G[12];
    quat2mat_dev(qw, qx, qy, qz, G);
    G[9] = rel[0]; G[10] = rel[1]; G[11] = rel[2];
    if (u == 5) {
      write_A(Ar, G, Jk);
    } else {
      for (int mstep = 0; mstep < 3; ++mstep) {
        int j = 3*u + 1 + mstep;
        int i = j - 1;
        float tx = theta[b*45 + 3*i + 0];
        float ty = theta[b*45 + 3*i + 1];
        float tz = theta[b*45 + 3*i + 2];
        float R[9];
        rodrigues_dev(tx, ty, tz, R);
        pf[9*i+0] = R[0]-1.f; pf[9*i+1] = R[1];     pf[9*i+2] = R[2];
        pf[9*i+3] = R[3];     pf[9*i+4] = R[4]-1.f; pf[9*i+5] = R[5];
        pf[9*i+6] = R[6];     pf[9*i+7] = R[7];     pf[9*i+8] = R[8]-1.f;
        float nG[12];
        const float* rj = rel + j*3;
        #pragma unroll
        for (int r3 = 0; r3 < 3; ++r3) {
          float a0 = G[r3*3+0], a1 = G[r3*3+1], a2 = G[r3*3+2];
          nG[r3*3+0] = a0*R[0] + a1*R[3] + a2*R[6];
          nG[r3*3+1] = a0*R[1] + a1*R[4] + a2*R[7];
          nG[r3*3+2] = a0*R[2] + a1*R[5] + a2*R[8];
          nG[9+r3]   = G[9+r3] + a0*rj[0] + a1*rj[1] + a2*rj[2];
        }
        #pragma unroll
        for (int k = 0; k < 12; ++k) G[k] = nG[k];
        write_A(Ar + j*12, G, Jk + j*3);
      }
    }
  } else {
    for (int i = tid - 96; i < 336; i += 224) s_C1[i] = ws[OFF_C1 + i];
  }

  int bg = tid / HQ;
  int tq = tid - bg*HQ;
  bool act = (tid < 4*HQ);

  float4 acc[4][2];
  const float4* C04 = (const float4*)(ws + OFF_C0);
  if (act) {
    #pragma unroll
    for (int k = 0; k < 2; ++k) {
      float4 c0 = C04[j2base*12 + tq + k*HQ];
      acc[0][k] = c0; acc[1][k] = c0; acc[2][k] = c0; acc[3][k] = c0;
    }
  }

  // ---- MAC loop over p in chunks of 8 ----
  float4* sP4 = (float4*)s_PM;
  const float4* gP4 = (const float4*)(ws + OFF_P);
  for (int pc = 0; pc < NP; pc += 8) {
    int cn = min(8, NP - pc);
    int n = cn * QF4;
    __syncthreads();   // prev chunk consumed (also covers pose prologue on 1st iter)
    for (int i = tid; i < n; i += 320) {
      int pp = i / QF4, f = i - pp*QF4;
      sP4[i] = gP4[(pc+pp)*252 + j2base*12 + f];
    }
    __syncthreads();
    if (act) {
      for (int pp = 0; pp < cn; ++pp) {
        float4 pv0 = sP4[pp*QF4 + tq];
        float4 pv1 = sP4[pp*QF4 + tq + HQ];
        #pragma unroll
        for (int bb = 0; bb < 4; ++bb) {
          float s = s_pf[(bg*4+bb)*136 + pc + pp];
          acc[bb][0].x += s*pv0.x; acc[bb][0].y += s*pv0.y;
          acc[bb][0].z += s*pv0.z; acc[bb][0].w += s*pv0.w;
          acc[bb][1].x += s*pv1.x; acc[bb][1].y += s*pv1.y;
          acc[bb][1].z += s*pv1.z; acc[bb][1].w += s*pv1.w;
        }
      }
    }
  }
  __syncthreads();   // all P reads done; s_PM becomes M spill

  // ---- epilogue: 2 passes of 8 batches ----
  float* s_M = s_PM;
  for (int pass = 0; pass < 2; ++pass) {
    if (pass) __syncthreads();   // pass-0 contraction done before overwrite
    if (act && (bg >> 1) == pass) {
      int bbase = (bg & 1) * 4;
      #pragma unroll
      for (int bb = 0; bb < 4; ++bb) {
        float4* dst = (float4*)(s_M + (size_t)(bbase+bb)*RSfl);
        dst[tq]      = acc[bb][0];
        dst[tq + HQ] = acc[bb][1];
      }
    }
    __syncthreads();
    int nc = 8 * NJ2H;    // 80 / 88 outputs this pass
    if (tid < nc) {
      int bbl = tid / NJ2H, j2l = tid - bbl*NJ2H;
      int j2 = j2base + j2l;
      int brow = pass*8 + bbl;
      int b = b0 + brow;
      const float* mrow = s_M + (size_t)bbl*RSfl + j2l*48;
      const float* c1p  = s_C1 + j2*16;
      const float* Ab   = s_A + brow*192;
      float a0=0.f, a1=0.f, a2=0.f;
      #pragma unroll
      for (int j = 0; j < 16; ++j) {
        float m0 = mrow[3*j+0], m1 = mrow[3*j+1], m2 = mrow[3*j+2];
        float c1v = c1p[j];
        const float* Aj = Ab + j*12;
        a0 += Aj[0]*m0 + Aj[1]*m1 + Aj[2]*m2  + Aj[3]*c1v;
        a1 += Aj[4]*m0 + Aj[5]*m1 + Aj[6]*m2  + Aj[7]*c1v;
        a2 += Aj[8]*m0 + Aj[9]*m1 + Aj[10]*m2 + Aj[11]*c1v;
      }
      out[(size_t)(b*21 + j2)*3 + 0] = a0 + init_trans[b*3+0];
      out[(size_t)(b*21 + j2)*3 + 1] = a1 + init_trans[b*3+1];
      out[(size_t)(b*21 + j2)*3 + 2] = a2 + init_trans[b*3+2];
    }
  }
}

extern "C" void kernel_launch(void* const* d_in, const int* in_sizes, int n_in,
                              void* d_out, int out_size, void* d_ws, size_t ws_size,
                              hipStream_t stream) {
  const float* theta       = (const float*)d_in[0];
  const float* delta_quat  = (const float*)d_in[1];
  const float* user_shape  = (const float*)d_in[2];
  const float* init_quat   = (const float*)d_in[3];
  const float* init_trans  = (const float*)d_in[4];
  const float* v_template  = (const float*)d_in[5];
  const float* shapedirs   = (const float*)d_in[6];
  const float* J_regressor = (const float*)d_in[7];
  const float* posedirs    = (const float*)d_in[8];
  const float* weights     = (const float*)d_in[9];
  float* out = (float*)d_out;
  float* ws  = (float*)d_ws;

  hipMemsetAsync((char*)d_ws + (size_t)OFF_C1*4, 0, (size_t)(WS_END - OFF_C1)*4, stream);
  k1_shape<<<1, 256, 0, stream>>>(user_shape, v_template, shapedirs, J_regressor, ws);
  k3_pgemm<<<26*8, 192, 0, stream>>>(J_regressor, weights, posedirs,
                                     user_shape, v_template, shapedirs, ws);
  k5_main<<<1024, 320, 0, stream>>>(theta, delta_quat, init_quat, init_trans, ws, out);
}

// Round 5
// 227.933 us; speedup vs baseline: 1.2490x; 1.2490x over previous
//
#include <hip/hip_runtime.h>
#include <math.h>

#define B_SIZE 8192
#define NVERT 778
#define NP 135

// ---- workspace layout (floats) ----
#define OFF_JK   0         // 48
#define OFF_C1   64        // 336  (21 x 16)
#define OFF_C0   400       // 1008 (21 x 48), 16B aligned
#define OFF_P2   1408      // 21*135*48 = 136080, 16B aligned rows of 48
#define OFF_PFT  137488    // 135 x 8192 (p-major, b minor)
#define OFF_AT   1243408   // 192 x 8192 (o-major, b minor)
#define WS_END   2816272   // 11.27 MB

__device__ inline void quat2mat_dev(float qw, float qx, float qy, float qz, float* R) {
  float n = sqrtf(qw*qw + qx*qx + qy*qy + qz*qz);
  float w = qw/n, x = qx/n, y = qy/n, z = qz/n;
  float w2=w*w, x2=x*x, y2=y*y, z2=z*z;
  float wx=w*x, wy=w*y, wz=w*z, xy=x*y, xz=x*z, yz=y*z;
  R[0]=w2+x2-y2-z2; R[1]=2.f*xy-2.f*wz; R[2]=2.f*wy+2.f*xz;
  R[3]=2.f*wz+2.f*xy; R[4]=w2-x2+y2-z2; R[5]=2.f*yz-2.f*wx;
  R[6]=2.f*xz-2.f*wy; R[7]=2.f*wx+2.f*yz; R[8]=w2-x2-y2+z2;
}

__device__ inline void rodrigues_dev(float tx, float ty, float tz, float* R) {
  float ax = tx + 1e-8f, ay = ty + 1e-8f, az = tz + 1e-8f;
  float angle = sqrtf(ax*ax + ay*ay + az*az);
  float nx = tx/angle, ny = ty/angle, nz = tz/angle;
  float half = 0.5f*angle;
  float cw = cosf(half), sw = sinf(half);
  quat2mat_dev(cw, sw*nx, sw*ny, sw*nz, R);
}

// kPre: blocks 0..207 = P2/C0/C1 GEMM (atomic accumulate, ws pre-zeroed);
//       blocks 208..223 = Jk[j] regression (j = bid-208).
__global__ __launch_bounds__(192) void kPre(const float* __restrict__ J_regressor,
                                            const float* __restrict__ weights,
                                            const float* __restrict__ posedirs,
                                            const float* __restrict__ user_shape,
                                            const float* __restrict__ v_template,
                                            const float* __restrict__ shapedirs,
                                            float* __restrict__ ws) {
  int tid = threadIdx.x;
  int bid = blockIdx.x;
  __shared__ float ush[10];
  if (tid < 10) ush[tid] = user_shape[tid];

  if (bid >= 208) {
    // ---- Jk block: Jk[j][c] = sum_v vs[v][c] * JR[v][j] ----
    int j = bid - 208;
    __shared__ float red[3*192];
    float p0 = 0.f, p1 = 0.f, p2 = 0.f;
    __syncthreads();  // ush visible
    for (int v = tid; v < NVERT; v += 192) {
      float jr = J_regressor[v*21 + j];
      #pragma unroll
      for (int c = 0; c < 3; ++c) {
        int e = 3*v + c;
        float t = v_template[e];
        #pragma unroll
        for (int s = 0; s < 10; ++s) t += ush[s]*shapedirs[s*2334 + e];
        float val = jr * t;
        if (c == 0) p0 += val; else if (c == 1) p1 += val; else p2 += val;
      }
    }
    red[0*192+tid] = p0; red[1*192+tid] = p1; red[2*192+tid] = p2;
    __syncthreads();
    if (tid < 3) {
      float s = 0.f;
      for (int t = 0; t < 192; ++t) s += red[tid*192 + t];
      ws[OFF_JK + j*3 + tid] = s;
    }
    return;
  }

  // ---- GEMM block: 26 col-groups x 8 ksplit ----
  __shared__ float sJR[64*21];
  __shared__ float sW [64*16];
  __shared__ float sB [64*16];
  int ng = bid % 26;
  int ks = bid / 26;
  int vbeg = ks*98;
  int vend = min(NVERT, vbeg + 98);

  int cg = (tid < 84) ? 0 : 1;
  int r4 = (tid < 84) ? tid : tid - 84;
  bool act = (tid < 168);
  int q2 = 4*r4;
  int j2 = q2 >> 4;
  int jb = q2 & 15;

  float acc[4][8];
  #pragma unroll
  for (int r = 0; r < 4; ++r)
    #pragma unroll
    for (int s = 0; s < 8; ++s) acc[r][s] = 0.f;

  for (int v0 = vbeg; v0 < vend; v0 += 64) {
    int kt = min(64, vend - v0);
    __syncthreads();
    for (int idx = tid; idx < kt*21; idx += 192) sJR[idx] = J_regressor[v0*21 + idx];
    for (int idx = tid; idx < kt*16; idx += 192) sW[idx]  = weights[v0*16 + idx];
    for (int idx = tid; idx < 16*64; idx += 192) {
      int s = idx >> 6, iv = idx & 63;
      if (iv < kt) {
        int ec = ng*16 + s;
        float val;
        if (ec > 408) val = 0.f;
        else if (ec == 408) val = 1.f;
        else {
          int c = ec / 136, pp = ec - c*136;
          int e = 3*(v0+iv) + c;
          if (pp == 135) {
            float t = v_template[e];
            #pragma unroll
            for (int s0 = 0; s0 < 10; ++s0) t += ush[s0]*shapedirs[s0*2334 + e];
            val = t;
          } else {
            val = posedirs[pp*2334 + e];
          }
        }
        sB[iv*16 + s] = val;
      }
    }
    __syncthreads();
    if (act) {
      for (int i = 0; i < kt; ++i) {
        float jr = sJR[i*21 + j2];
        float4 w4 = *(const float4*)&sW[i*16 + jb];
        float4 b0 = *(const float4*)&sB[i*16 + cg*8];
        float4 b1 = *(const float4*)&sB[i*16 + cg*8 + 4];
        float wv[4] = {w4.x, w4.y, w4.z, w4.w};
        #pragma unroll
        for (int r = 0; r < 4; ++r) {
          float s2 = jr * wv[r];
          acc[r][0] += s2*b0.x; acc[r][1] += s2*b0.y;
          acc[r][2] += s2*b0.z; acc[r][3] += s2*b0.w;
          acc[r][4] += s2*b1.x; acc[r][5] += s2*b1.y;
          acc[r][6] += s2*b1.z; acc[r][7] += s2*b1.w;
        }
      }
    }
  }
  if (act) {
    #pragma unroll
    for (int s = 0; s < 8; ++s) {
      int ec = ng*16 + cg*8 + s;
      if (ec > 408) continue;
      #pragma unroll
      for (int r = 0; r < 4; ++r) {
        float v = acc[r][s];
        int q2r = q2 + r;
        int jj2 = q2r >> 4, jj = q2r & 15;
        if (ec == 408) {
          atomicAdd(ws + OFF_C1 + jj2*16 + jj, v);
        } else {
          int c = ec / 136, pp = ec - c*136;
          if (pp == 135) atomicAdd(ws + OFF_C0 + jj2*48 + jj*3 + c, v);
          else           atomicAdd(ws + OFF_P2 + (size_t)(jj2*135 + pp)*48 + jj*3 + c, v);
        }
      }
    }
  }
}

// k4: one thread per batch. Pose chain -> pfT[p][b] (transposed) + AT[o][b] (transposed).
__global__ __launch_bounds__(256) void k4_pose(const float* __restrict__ theta,
                                               const float* __restrict__ delta_quat,
                                               const float* __restrict__ init_quat,
                                               float* __restrict__ ws) {
  int b = blockIdx.x*256 + threadIdx.x;
  __shared__ float jk[48], rel[48];
  if (threadIdx.x < 48) {
    float v = ws[OFF_JK + threadIdx.x];
    jk[threadIdx.x] = v;
    int j = threadIdx.x/3, c = threadIdx.x - j*3;
    float r;
    if (j == 0) r = v;
    else {
      int par = (((j-1) % 3) == 0) ? 0 : (j-1);
      r = v - ws[OFF_JK + par*3 + c];
    }
    rel[threadIdx.x] = r;
  }
  __syncthreads();
  float* pfT = ws + OFF_PFT;
  float* AT  = ws + OFF_AT;

  float w1=delta_quat[b*4+0], x1=delta_quat[b*4+1], y1=delta_quat[b*4+2], z1=delta_quat[b*4+3];
  float w2=init_quat[0], x2=init_quat[1], y2=init_quat[2], z2=init_quat[3];
  float qw = w1*w2 - x1*x2 - y1*y2 - z1*z2;
  float qx = w1*x2 + x1*w2 + y1*z2 - z1*y2;
  float qy = w1*y2 - x1*z2 + y1*w2 + z1*x2;
  float qz = w1*z2 + x1*y2 - y1*x2 + z1*w2;
  float Gr[12];
  quat2mat_dev(qw, qx, qy, qz, Gr);
  Gr[9] = rel[0]; Gr[10] = rel[1]; Gr[11] = rel[2];
  // A for joint 0
  #pragma unroll
  for (int c = 0; c < 3; ++c) {
    float g0 = Gr[c*3+0], g1 = Gr[c*3+1], g2 = Gr[c*3+2];
    AT[(size_t)(c*4+0)*B_SIZE + b] = g0;
    AT[(size_t)(c*4+1)*B_SIZE + b] = g1;
    AT[(size_t)(c*4+2)*B_SIZE + b] = g2;
    AT[(size_t)(c*4+3)*B_SIZE + b] = Gr[9+c] - (g0*jk[0] + g1*jk[1] + g2*jk[2]);
  }
  for (int u = 0; u < 5; ++u) {
    float G[12];
    #pragma unroll
    for (int k = 0; k < 12; ++k) G[k] = Gr[k];
    for (int mstep = 0; mstep < 3; ++mstep) {
      int j = 3*u + 1 + mstep;
      int i = j - 1;
      float tx = theta[b*45 + 3*i + 0];
      float ty = theta[b*45 + 3*i + 1];
      float tz = theta[b*45 + 3*i + 2];
      float R[9];
      rodrigues_dev(tx, ty, tz, R);
      pfT[(size_t)(9*i+0)*B_SIZE + b] = R[0]-1.f;
      pfT[(size_t)(9*i+1)*B_SIZE + b] = R[1];
      pfT[(size_t)(9*i+2)*B_SIZE + b] = R[2];
      pfT[(size_t)(9*i+3)*B_SIZE + b] = R[3];
      pfT[(size_t)(9*i+4)*B_SIZE + b] = R[4]-1.f;
      pfT[(size_t)(9*i+5)*B_SIZE + b] = R[5];
      pfT[(size_t)(9*i+6)*B_SIZE + b] = R[6];
      pfT[(size_t)(9*i+7)*B_SIZE + b] = R[7];
      pfT[(size_t)(9*i+8)*B_SIZE + b] = R[8]-1.f;
      float nG[12];
      const float* rj = rel + j*3;
      #pragma unroll
      for (int r3 = 0; r3 < 3; ++r3) {
        float a0 = G[r3*3+0], a1 = G[r3*3+1], a2 = G[r3*3+2];
        nG[r3*3+0] = a0*R[0] + a1*R[3] + a2*R[6];
        nG[r3*3+1] = a0*R[1] + a1*R[4] + a2*R[7];
        nG[r3*3+2] = a0*R[2] + a1*R[5] + a2*R[8];
        nG[9+r3]   = G[9+r3] + a0*rj[0] + a1*rj[1] + a2*rj[2];
      }
      #pragma unroll
      for (int k = 0; k < 12; ++k) G[k] = nG[k];
      const float* jkj = jk + j*3;
      #pragma unroll
      for (int c = 0; c < 3; ++c) {
        float g0 = G[c*3+0], g1 = G[c*3+1], g2 = G[c*3+2];
        AT[(size_t)(j*12 + c*4+0)*B_SIZE + b] = g0;
        AT[(size_t)(j*12 + c*4+1)*B_SIZE + b] = g1;
        AT[(size_t)(j*12 + c*4+2)*B_SIZE + b] = g2;
        AT[(size_t)(j*12 + c*4+3)*B_SIZE + b] = G[9+c] - (g0*jkj[0] + g1*jkj[1] + g2*jkj[2]);
      }
    }
  }
}

// k5: lane = batch, block = 256 batches x 1 j2. No LDS, no barriers in hot loop.
// M[b][j2][0..47] = C0 + sum_p pfT[p][b] * P2[j2][p][:], then thread-local A-contraction.
__global__ __launch_bounds__(256) void k5_main(const float* __restrict__ init_trans,
                                               const float* __restrict__ ws,
                                               float* __restrict__ out) {
  int j2 = blockIdx.x % 21;
  int b  = (blockIdx.x / 21) * 256 + threadIdx.x;

  float4 acc[12];
  const float4* c04 = (const float4*)(ws + OFF_C0 + j2*48);
  #pragma unroll
  for (int i = 0; i < 12; ++i) acc[i] = c04[i];

  const float* pfT = ws + OFF_PFT;
  const float4* P24 = (const float4*)(ws + OFF_P2);
  #pragma unroll 3
  for (int p = 0; p < NP; ++p) {
    float pf = pfT[(size_t)p*B_SIZE + b];
    const float4* Pr = P24 + (size_t)(j2*135 + p)*12;
    #pragma unroll
    for (int i = 0; i < 12; ++i) {
      float4 pv = Pr[i];
      acc[i].x += pf*pv.x; acc[i].y += pf*pv.y;
      acc[i].z += pf*pv.z; acc[i].w += pf*pv.w;
    }
  }

  float m[48];
  #pragma unroll
  for (int i = 0; i < 12; ++i) {
    m[4*i+0] = acc[i].x; m[4*i+1] = acc[i].y;
    m[4*i+2] = acc[i].z; m[4*i+3] = acc[i].w;
  }

  const float* AT  = ws + OFF_AT;
  const float* c1p = ws + OFF_C1 + j2*16;
  float o0 = 0.f, o1 = 0.f, o2 = 0.f;
  #pragma unroll
  for (int j = 0; j < 16; ++j) {
    float c1 = c1p[j];
    float m0 = m[3*j+0], m1 = m[3*j+1], m2 = m[3*j+2];
    #pragma unroll
    for (int k = 0; k < 3; ++k) {
      float a0 = AT[(size_t)(j*12 + k*4+0)*B_SIZE + b];
      float a1 = AT[(size_t)(j*12 + k*4+1)*B_SIZE + b];
      float a2 = AT[(size_t)(j*12 + k*4+2)*B_SIZE + b];
      float a3 = AT[(size_t)(j*12 + k*4+3)*B_SIZE + b];
      float r = a0*m0 + a1*m1 + a2*m2 + a3*c1;
      if (k == 0) o0 += r; else if (k == 1) o1 += r; else o2 += r;
    }
  }
  size_t ob = ((size_t)b*21 + j2)*3;
  out[ob+0] = o0 + init_trans[b*3+0];
  out[ob+1] = o1 + init_trans[b*3+1];
  out[ob+2] = o2 + init_trans[b*3+2];
}

extern "C" void kernel_launch(void* const* d_in, const int* in_sizes, int n_in,
                              void* d_out, int out_size, void* d_ws, size_t ws_size,
                              hipStream_t stream) {
  const float* theta       = (const float*)d_in[0];
  const float* delta_quat  = (const float*)d_in[1];
  const float* user_shape  = (const float*)d_in[2];
  const float* init_quat   = (const float*)d_in[3];
  const float* init_trans  = (const float*)d_in[4];
  const float* v_template  = (const float*)d_in[5];
  const float* shapedirs   = (const float*)d_in[6];
  const float* J_regressor = (const float*)d_in[7];
  const float* posedirs    = (const float*)d_in[8];
  const float* weights     = (const float*)d_in[9];
  float* out = (float*)d_out;
  float* ws  = (float*)d_ws;

  // zero C1/C0/P2 (atomic accumulation targets)
  hipMemsetAsync((char*)d_ws + (size_t)OFF_C1*4, 0,
                 (size_t)(OFF_P2 + 21*135*48 - OFF_C1)*4, stream);
  kPre<<<224, 192, 0, stream>>>(J_regressor, weights, posedirs,
                                user_shape, v_template, shapedirs, ws);
  k4_pose<<<32, 256, 0, stream>>>(theta, delta_quat, init_quat, ws);
  k5_main<<<32*21, 256, 0, stream>>>(init_trans, ws, out);
}